// Round 4
// baseline (166.704 us; speedup 1.0000x reference)
//
#include <hip/hip_runtime.h>
#include <hip/hip_bf16.h>
#include <stdint.h>

// Problem constants: B=8, T=1024, C=768, H=12, hs=64
#define T_ 1024
#define C_ 768
#define H_ 12
#define HS 64

typedef __attribute__((ext_vector_type(8))) short bf16x8;
typedef __attribute__((ext_vector_type(4))) float f32x4;

#define GLOAD16(g, l) __builtin_amdgcn_global_load_lds( \
    (const __attribute__((address_space(1))) uint32_t*)(g), \
    (__attribute__((address_space(3))) uint32_t*)(l), 16, 0, 0)

#define WAITCNT_VM(n) asm volatile("s_waitcnt vmcnt(" #n ")" ::: "memory")

__device__ __forceinline__ ushort f2b(float f) {
  uint32_t u = __builtin_bit_cast(uint32_t, f);
  u = (u + 0x7fffu + ((u >> 16) & 1u)) >> 16;   // RNE
  return (ushort)u;
}

// ---------------------------------------------------------------- convert
__global__ __launch_bounds__(256) void cvt_bf16(
    const float* __restrict__ x, const float* __restrict__ wt,
    ushort* __restrict__ xb, ushort* __restrict__ wb) {
  const int NX4 = 8192 * 768 / 4;
  const int NW4 = 2304 * 768 / 4;
  int i = blockIdx.x * 256 + threadIdx.x;
  int stride = gridDim.x * 256;
  for (int idx = i; idx < NX4; idx += stride) {
    float4 f = ((const float4*)x)[idx];
    ushort4 o;
    o.x = f2b(f.x); o.y = f2b(f.y); o.z = f2b(f.z); o.w = f2b(f.w);
    ((ushort4*)xb)[idx] = o;
  }
  for (int idx = i; idx < NW4; idx += stride) {
    float4 f = ((const float4*)wt)[idx];
    ushort4 o;
    o.x = f2b(f.x); o.y = f2b(f.y); o.z = f2b(f.z); o.w = f2b(f.w);
    ((ushort4*)wb)[idx] = o;
  }
}

// ---------------------------------------------------------------- qkv gemm
// C[m,n] = sum_k xb[m,k]*wb[n,k] + bias[n].
// 128x128 tile, BK=32, 4 waves. 3-buffer LDS pipeline, 2-deep prefetch,
// counted vmcnt(4) + raw s_barrier (never drain to 0 mid-loop).
// XCD-swizzled block order: each XCD gets 8 contiguous m-panels (L2-fit).
// Q/K epilogue re-tiled through LDS for 16B/lane stores; V stored transposed.
__global__ __launch_bounds__(256) void qkv_gemm(
    const ushort* __restrict__ xb, const ushort* __restrict__ wb,
    const float* __restrict__ bias,
    ushort* __restrict__ qo, ushort* __restrict__ ko, ushort* __restrict__ vT) {
  __shared__ __align__(16) char smem[49152];   // 3 stages x (A 8KB + B 8KB)
  const int tid = threadIdx.x, lane = tid & 63, w = tid >> 6;
  const int g = lane >> 4, l15 = lane & 15;
  // bijective XCD swizzle: 1152 blocks, XCD k gets ids [k*144,(k+1)*144)
  const int id = blockIdx.x;
  const int wg = (id & 7) * 144 + (id >> 3);
  const int m0 = (wg / 18) * 128, n0 = (wg % 18) * 128;
  const int wr = w >> 1, wc = w & 1;
  f32x4 acc[4][4] = {};

  // staging: A tile 128x32 = 512 16B-slots, 2/thread (same B)
  const ushort* srcA[2];
  const ushort* srcB[2];
  int dstoff[2];
  #pragma unroll
  for (int c = 0; c < 2; ++c) {
    int p = (c * 4 + w) * 64 + lane;
    int row = p >> 2, s = p & 3;
    int sc = (s ^ ((row >> 1) & 3)) * 8;      // pre-swizzled source col
    srcA[c] = xb + (size_t)(m0 + row) * 768 + sc;
    srcB[c] = wb + (size_t)(n0 + row) * 768 + sc;
    dstoff[c] = (c * 4 + w) * 1024;
  }

#define STAGE_G(bb_, k0) do { \
    _Pragma("unroll") \
    for (int c_ = 0; c_ < 2; ++c_) { \
      GLOAD16(srcA[c_] + (k0), (bb_) + dstoff[c_]); \
      GLOAD16(srcB[c_] + (k0), (bb_) + 8192 + dstoff[c_]); \
    } \
  } while (0)

#define GEMM_COMPUTE(cb_) do { \
    bf16x8 af[4], bfr[4]; \
    _Pragma("unroll") \
    for (int mi = 0; mi < 4; ++mi) { \
      int r_ = wr * 64 + mi * 16 + l15; \
      af[mi] = *(const bf16x8*)((cb_) + r_ * 64 + ((g ^ ((r_ >> 1) & 3)) << 4)); \
    } \
    _Pragma("unroll") \
    for (int ni = 0; ni < 4; ++ni) { \
      int r_ = wc * 64 + ni * 16 + l15; \
      bfr[ni] = *(const bf16x8*)((cb_) + 8192 + r_ * 64 + ((g ^ ((r_ >> 1) & 3)) << 4)); \
    } \
    __builtin_amdgcn_s_setprio(1); \
    _Pragma("unroll") \
    for (int mi = 0; mi < 4; ++mi) \
      _Pragma("unroll") \
      for (int ni = 0; ni < 4; ++ni) \
        acc[mi][ni] = __builtin_amdgcn_mfma_f32_16x16x32_bf16(af[mi], bfr[ni], acc[mi][ni], 0, 0, 0); \
    __builtin_amdgcn_s_setprio(0); \
  } while (0)

  STAGE_G(smem, 0);
  STAGE_G(smem + 16384, 32);
  char* cptr = smem;
  char* sptr = smem + 32768;
  for (int kk = 0; kk < 23; ++kk) {
    WAITCNT_VM(4);                     // stage kk complete; kk+1 stays in flight
    __builtin_amdgcn_s_barrier();
    if (kk < 22) STAGE_G(sptr, (kk + 2) * 32);
    GEMM_COMPUTE(cptr);
    cptr += 16384; if (cptr == smem + 49152) cptr = smem;
    sptr += 16384; if (sptr == smem + 49152) sptr = smem;
  }
  WAITCNT_VM(0);
  __builtin_amdgcn_s_barrier();
  GEMM_COMPUTE(cptr);
  __syncthreads();   // all waves done with LDS before epilogue reuse

  const int which = n0 / 768;   // 768 % 128 == 0 -> block-uniform
  if (which < 2) {
    ushort* outp = (which == 0) ? qo : ko;
    // acc -> LDS [ml][nl] (XOR-swizzled), then 16B/lane coalesced stores
    #pragma unroll
    for (int ni = 0; ni < 4; ++ni) {
      float bn = bias[n0 + wc * 64 + ni * 16 + l15];
      int nl = wc * 64 + ni * 16 + l15;
      #pragma unroll
      for (int mi = 0; mi < 4; ++mi) {
        #pragma unroll
        for (int r = 0; r < 4; ++r) {
          int ml = wr * 64 + mi * 16 + g * 4 + r;
          *(ushort*)(smem + ml * 256 + ((nl * 2) ^ ((ml & 7) << 4))) =
              f2b(acc[mi][ni][r] + bn);
        }
      }
    }
    __syncthreads();
    #pragma unroll
    for (int c = 0; c < 8; ++c) {
      int p = c * 256 + tid;
      int ml = p >> 4, nch = p & 15;
      uint4 val = *(const uint4*)(smem + ml * 256 + ((nch * 16) ^ ((ml & 7) << 4)));
      int m = m0 + ml;
      int nin = n0 + nch * 8 - which * 768;
      int h = nin >> 6, d = nin & 63;
      *(uint4*)(outp + ((size_t)((m >> 10) * H_ + h) * T_ + (m & (T_ - 1))) * HS + d) = val;
    }
  } else {
    // V: transpose 128x128 through LDS, store [B,H,hs,T] coalesced
    #pragma unroll
    for (int ni = 0; ni < 4; ++ni) {
      float bn = bias[n0 + wc * 64 + ni * 16 + l15];
      int dl = wc * 64 + ni * 16 + l15;
      #pragma unroll
      for (int mi = 0; mi < 4; ++mi) {
        #pragma unroll
        for (int r = 0; r < 4; ++r) {
          int tl = wr * 64 + mi * 16 + g * 4 + r;
          *(ushort*)(smem + dl * 256 + ((tl * 2) ^ ((dl & 7) << 4))) =
              f2b(acc[mi][ni][r] + bn);
        }
      }
    }
    __syncthreads();
    const int b = m0 >> 10, t0base = m0 & 1023;
    #pragma unroll
    for (int c = 0; c < 8; ++c) {
      int p = c * 256 + tid;
      int dl = p >> 4, tch = p & 15;
      uint4 val = *(const uint4*)(smem + dl * 256 + ((tch * 16) ^ ((dl & 7) << 4)));
      int nin = n0 + dl - 1536;
      int h = nin >> 6, dd = nin & 63;
      *(uint4*)(vT + (((size_t)(b * H_ + h) * HS + dd) << 10) + t0base + tch * 8) = val;
    }
  }
}

// ---------------------------------------------------------------- attention
// One block = one (bh, 64-row q-tile). 4 waves, each owns 16 q-rows.
// ReLU attention (no softmax state); causal -> k-tiles 0..qt only.
// Q in regs; K/V 3-buffer LDS pipeline, 2-deep prefetch, counted vmcnt.
// XCD swizzle: each XCD gets 12 consecutive heads (K/V L2 reuse).
__global__ __launch_bounds__(256) void attn_relu(
    const ushort* __restrict__ q, const ushort* __restrict__ k,
    const ushort* __restrict__ vT, float* __restrict__ out) {
  __shared__ __align__(16) char smem[57344];  // 3 x (K 8KB + V 8KB) + P 8KB
  const int tid = threadIdx.x, lane = tid & 63, w = tid >> 6;
  const int g = lane >> 4, l15 = lane & 15;
  const int id = blockIdx.x;
  const int wg = (id & 7) * 192 + (id >> 3);
  const int bh = wg >> 4;
  const int qt = 15 - (wg & 15);               // heavy q-tiles first
  const int q0 = qt * 64;
  const size_t base = (size_t)bh * (T_ * HS);
  const int qrow = w * 16 + l15;

  // Q fragments straight from global (once per block)
  bf16x8 qf[2];
  #pragma unroll
  for (int kd = 0; kd < 2; ++kd)
    qf[kd] = *(const bf16x8*)(q + base + (size_t)(q0 + qrow) * HS + (kd * 4 + g) * 8);

  // staging: K/V tiles 64x64 = 512 slots, 2/thread each
  int rowS[2], scS[2], dstoff[2];
  #pragma unroll
  for (int c = 0; c < 2; ++c) {
    int p = (c * 4 + w) * 64 + lane;
    rowS[c] = p >> 3;
    scS[c] = ((p & 7) ^ (rowS[c] & 7)) * 8;
    dstoff[c] = (c * 4 + w) * 1024;
  }

#define STAGE_KV(bb_, kt) do { \
    _Pragma("unroll") \
    for (int c_ = 0; c_ < 2; ++c_) { \
      GLOAD16(k + base + (size_t)((kt) * 64 + rowS[c_]) * HS + scS[c_], (bb_) + dstoff[c_]); \
      GLOAD16(vT + base + (size_t)rowS[c_] * T_ + (kt) * 64 + scS[c_], (bb_) + 8192 + dstoff[c_]); \
    } \
  } while (0)

  f32x4 yacc[4] = {};
  char* const Pb = smem + 49152;

#define ATTN_COMPUTE(cb_, kt) do { \
    const char* Kb = (cb_); \
    const char* Vb = (cb_) + 8192; \
    f32x4 sacc[4] = {}; \
    __builtin_amdgcn_s_setprio(1); \
    _Pragma("unroll") \
    for (int kd = 0; kd < 2; ++kd) { \
      _Pragma("unroll") \
      for (int nt = 0; nt < 4; ++nt) { \
        int kr = nt * 16 + l15; \
        bf16x8 kf = *(const bf16x8*)(Kb + kr * 128 + (((kd * 4 + g) ^ (kr & 7)) << 4)); \
        sacc[nt] = __builtin_amdgcn_mfma_f32_16x16x32_bf16(qf[kd], kf, sacc[nt], 0, 0, 0); \
      } \
    } \
    __builtin_amdgcn_s_setprio(0); \
    _Pragma("unroll") \
    for (int nt = 0; nt < 4; ++nt) { \
      int kj = (kt) * 64 + nt * 16 + l15; \
      _Pragma("unroll") \
      for (int r = 0; r < 4; ++r) { \
        int i_ = w * 16 + g * 4 + r; \
        float sv = sacc[nt][r] * 0.125f; \
        float pv = (kj <= q0 + i_) ? fmaxf(sv, 0.0f) : 0.0f; \
        *(ushort*)(Pb + i_ * 128 + (((nt * 16 + l15) * 2) ^ ((i_ & 7) << 4))) = f2b(pv); \
      } \
    } \
    bf16x8 pf[2], vf[2][4]; \
    _Pragma("unroll") \
    for (int kj2 = 0; kj2 < 2; ++kj2) { \
      pf[kj2] = *(const bf16x8*)(Pb + qrow * 128 + (((kj2 * 4 + g) ^ (qrow & 7)) << 4)); \
      _Pragma("unroll") \
      for (int nt = 0; nt < 4; ++nt) { \
        int vr = nt * 16 + l15; \
        vf[kj2][nt] = *(const bf16x8*)(Vb + vr * 128 + (((kj2 * 4 + g) ^ (vr & 7)) << 4)); \
      } \
    } \
    __builtin_amdgcn_s_setprio(1); \
    _Pragma("unroll") \
    for (int kj2 = 0; kj2 < 2; ++kj2) \
      _Pragma("unroll") \
      for (int nt = 0; nt < 4; ++nt) \
        yacc[nt] = __builtin_amdgcn_mfma_f32_16x16x32_bf16(pf[kj2], vf[kj2][nt], yacc[nt], 0, 0, 0); \
    __builtin_amdgcn_s_setprio(0); \
  } while (0)

  const int nkt = qt + 1;
  STAGE_KV(smem, 0);
  if (nkt > 1) STAGE_KV(smem + 16384, 1);
  char* cptr = smem;
  char* sptr = smem + 32768;
  for (int kt = 0; kt < nkt - 1; ++kt) {
    WAITCNT_VM(4);
    __builtin_amdgcn_s_barrier();
    if (kt + 2 < nkt) STAGE_KV(sptr, kt + 2);
    ATTN_COMPUTE(cptr, kt);
    cptr += 16384; if (cptr == smem + 49152) cptr = smem;
    sptr += 16384; if (sptr == smem + 49152) sptr = smem;
  }
  WAITCNT_VM(0);
  __builtin_amdgcn_s_barrier();
  ATTN_COMPUTE(cptr, nkt - 1);

  // epilogue: out[b][t][h*64+d] (f32)
  const int bb = bh / H_, hh = bh % H_;
  #pragma unroll
  for (int nt = 0; nt < 4; ++nt) {
    #pragma unroll
    for (int r = 0; r < 4; ++r) {
      int t = q0 + w * 16 + g * 4 + r;
      int col = hh * HS + nt * 16 + l15;
      out[(size_t)(bb * T_ + t) * C_ + col] = yacc[nt][r];
    }
  }
}

// ---------------------------------------------------------------- launch
extern "C" void kernel_launch(void* const* d_in, const int* in_sizes, int n_in,
                              void* d_out, int out_size, void* d_ws, size_t ws_size,
                              hipStream_t stream) {
  const float* x    = (const float*)d_in[0];
  const float* W    = (const float*)d_in[1];
  const float* bias = (const float*)d_in[2];
  float* out = (float*)d_out;

  char* ws = (char*)d_ws;
  ushort* xb = (ushort*)ws;                       // 8192*768*2  = 12582912 B
  ushort* wb = (ushort*)(ws + 12582912);          // 2304*768*2  =  3538944 B
  ushort* qb = (ushort*)(ws + 16121856);          // 12582912 B
  ushort* kb = (ushort*)(ws + 28704768);          // 12582912 B
  ushort* vT = (ushort*)(ws + 41287680);          // 12582912 B  [B,H,hs,T]

  cvt_bf16<<<2048, 256, 0, stream>>>(x, W, xb, wb);
  qkv_gemm<<<1152, 256, 0, stream>>>(xb, wb, bias, qb, kb, vT);
  attn_relu<<<1536, 256, 0, stream>>>(qb, kb, vT, out);
}

// Round 5
// 153.511 us; speedup vs baseline: 1.0859x; 1.0859x over previous
//
#include <hip/hip_runtime.h>
#include <hip/hip_bf16.h>
#include <stdint.h>

// Problem constants: B=8, T=1024, C=768, H=12, hs=64
#define T_ 1024
#define C_ 768
#define H_ 12
#define HS 64

typedef __attribute__((ext_vector_type(8))) short bf16x8;
typedef __attribute__((ext_vector_type(4))) float f32x4;
typedef __attribute__((ext_vector_type(16))) float f32x16;

#define GLOAD16(g, l) __builtin_amdgcn_global_load_lds( \
    (const __attribute__((address_space(1))) uint32_t*)(g), \
    (__attribute__((address_space(3))) uint32_t*)(l), 16, 0, 0)

#define WAITCNT_VM(n) asm volatile("s_waitcnt vmcnt(" #n ")" ::: "memory")

__device__ __forceinline__ ushort f2b(float f) {
  uint32_t u = __builtin_bit_cast(uint32_t, f);
  u = (u + 0x7fffu + ((u >> 16) & 1u)) >> 16;   // RNE
  return (ushort)u;
}

__device__ __forceinline__ uint cvtpk(float a, float b) {
  uint r;
  asm("v_cvt_pk_bf16_f32 %0, %1, %2" : "=v"(r) : "v"(a), "v"(b));
  return r;   // low16 = bf16(a), high16 = bf16(b)
}

// ---------------------------------------------------------------- convert
__global__ __launch_bounds__(256) void cvt_bf16(
    const float* __restrict__ x, const float* __restrict__ wt,
    ushort* __restrict__ xb, ushort* __restrict__ wb) {
  const int NX4 = 8192 * 768 / 4;
  const int NW4 = 2304 * 768 / 4;
  int i = blockIdx.x * 256 + threadIdx.x;
  int stride = gridDim.x * 256;
  for (int idx = i; idx < NX4; idx += stride) {
    float4 f = ((const float4*)x)[idx];
    ushort4 o;
    o.x = f2b(f.x); o.y = f2b(f.y); o.z = f2b(f.z); o.w = f2b(f.w);
    ((ushort4*)xb)[idx] = o;
  }
  for (int idx = i; idx < NW4; idx += stride) {
    float4 f = ((const float4*)wt)[idx];
    ushort4 o;
    o.x = f2b(f.x); o.y = f2b(f.y); o.z = f2b(f.z); o.w = f2b(f.w);
    ((ushort4*)wb)[idx] = o;
  }
}

// ---------------------------------------------------------------- qkv gemm
// 128x128 tile, BK=32, 4 waves. 5-stage LDS pipeline (80KB), depth-4
// prefetch, counted vmcnt (12/8/4/0 tail) + raw s_barrier.
// XCD-swizzled block order. Q/K scatter [B,H,T,hs]; V stored transposed.
__global__ __launch_bounds__(256) void qkv_gemm(
    const ushort* __restrict__ xb, const ushort* __restrict__ wb,
    const float* __restrict__ bias,
    ushort* __restrict__ qo, ushort* __restrict__ ko, ushort* __restrict__ vT) {
  __shared__ __align__(16) char smem[81920];   // 5 stages x (A 8KB + B 8KB)
  const int tid = threadIdx.x, lane = tid & 63, w = tid >> 6;
  const int g = lane >> 4, l15 = lane & 15;
  const int id = blockIdx.x;
  const int wg = (id & 7) * 144 + (id >> 3);   // bijective: 1152 = 8*144
  const int m0 = (wg / 18) * 128, n0 = (wg % 18) * 128;
  const int wr = w >> 1, wc = w & 1;
  f32x4 acc[4][4] = {};

  const ushort* srcA[2];
  const ushort* srcB[2];
  int dstoff[2];
  #pragma unroll
  for (int c = 0; c < 2; ++c) {
    int p = (c * 4 + w) * 64 + lane;
    int row = p >> 2, s = p & 3;
    int sc = (s ^ ((row >> 1) & 3)) * 8;      // pre-swizzled source col
    srcA[c] = xb + (size_t)(m0 + row) * 768 + sc;
    srcB[c] = wb + (size_t)(n0 + row) * 768 + sc;
    dstoff[c] = (c * 4 + w) * 1024;
  }

#define STAGE_G(bb_, k0) do { \
    _Pragma("unroll") \
    for (int c_ = 0; c_ < 2; ++c_) { \
      GLOAD16(srcA[c_] + (k0), (bb_) + dstoff[c_]); \
      GLOAD16(srcB[c_] + (k0), (bb_) + 8192 + dstoff[c_]); \
    } \
  } while (0)

#define GEMM_COMPUTE(cb_) do { \
    bf16x8 af[4], bfr[4]; \
    _Pragma("unroll") \
    for (int mi = 0; mi < 4; ++mi) { \
      int r_ = wr * 64 + mi * 16 + l15; \
      af[mi] = *(const bf16x8*)((cb_) + r_ * 64 + ((g ^ ((r_ >> 1) & 3)) << 4)); \
    } \
    _Pragma("unroll") \
    for (int ni = 0; ni < 4; ++ni) { \
      int r_ = wc * 64 + ni * 16 + l15; \
      bfr[ni] = *(const bf16x8*)((cb_) + 8192 + r_ * 64 + ((g ^ ((r_ >> 1) & 3)) << 4)); \
    } \
    __builtin_amdgcn_s_setprio(1); \
    _Pragma("unroll") \
    for (int mi = 0; mi < 4; ++mi) \
      _Pragma("unroll") \
      for (int ni = 0; ni < 4; ++ni) \
        acc[mi][ni] = __builtin_amdgcn_mfma_f32_16x16x32_bf16(af[mi], bfr[ni], acc[mi][ni], 0, 0, 0); \
    __builtin_amdgcn_s_setprio(0); \
  } while (0)

  STAGE_G(smem, 0);
  STAGE_G(smem + 16384, 32);
  STAGE_G(smem + 32768, 64);
  STAGE_G(smem + 49152, 96);
  char* cptr = smem;
  char* sptr = smem + 65536;
  for (int kk = 0; kk < 23; ++kk) {
    if (kk <= 20)      WAITCNT_VM(12);   // 3 stages (12 loads) stay in flight
    else if (kk == 21) WAITCNT_VM(8);
    else               WAITCNT_VM(4);
    __builtin_amdgcn_s_barrier();
    if (kk < 20) STAGE_G(sptr, (kk + 4) * 32);
    GEMM_COMPUTE(cptr);
    cptr += 16384; if (cptr == smem + 81920) cptr = smem;
    sptr += 16384; if (sptr == smem + 81920) sptr = smem;
  }
  WAITCNT_VM(0);
  __builtin_amdgcn_s_barrier();
  GEMM_COMPUTE(cptr);
  __syncthreads();   // all waves done with LDS before epilogue reuse

  const int which = n0 / 768;   // 768 % 128 == 0 -> block-uniform
  if (which < 2) {
    ushort* outp = (which == 0) ? qo : ko;
    #pragma unroll
    for (int ni = 0; ni < 4; ++ni) {
      float bn = bias[n0 + wc * 64 + ni * 16 + l15];
      int nl = wc * 64 + ni * 16 + l15;
      #pragma unroll
      for (int mi = 0; mi < 4; ++mi) {
        #pragma unroll
        for (int r = 0; r < 4; ++r) {
          int ml = wr * 64 + mi * 16 + g * 4 + r;
          *(ushort*)(smem + ml * 256 + ((nl * 2) ^ ((ml & 7) << 4))) =
              f2b(acc[mi][ni][r] + bn);
        }
      }
    }
    __syncthreads();
    #pragma unroll
    for (int c = 0; c < 8; ++c) {
      int p = c * 256 + tid;
      int ml = p >> 4, nch = p & 15;
      uint4 val = *(const uint4*)(smem + ml * 256 + ((nch * 16) ^ ((ml & 7) << 4)));
      int m = m0 + ml;
      int nin = n0 + nch * 8 - which * 768;
      int h = nin >> 6, d = nin & 63;
      *(uint4*)(outp + ((size_t)((m >> 10) * H_ + h) * T_ + (m & (T_ - 1))) * HS + d) = val;
    }
  } else {
    // V: transpose 128x128 through LDS, store [B,H,hs,T] coalesced
    #pragma unroll
    for (int ni = 0; ni < 4; ++ni) {
      float bn = bias[n0 + wc * 64 + ni * 16 + l15];
      int dl = wc * 64 + ni * 16 + l15;
      #pragma unroll
      for (int mi = 0; mi < 4; ++mi) {
        #pragma unroll
        for (int r = 0; r < 4; ++r) {
          int tl = wr * 64 + mi * 16 + g * 4 + r;
          *(ushort*)(smem + dl * 256 + ((tl * 2) ^ ((dl & 7) << 4))) =
              f2b(acc[mi][ni][r] + bn);
        }
      }
    }
    __syncthreads();
    const int b = m0 >> 10, t0base = m0 & 1023;
    #pragma unroll
    for (int c = 0; c < 8; ++c) {
      int p = c * 256 + tid;
      int dl = p >> 4, tch = p & 15;
      uint4 val = *(const uint4*)(smem + dl * 256 + ((tch * 16) ^ ((dl & 7) << 4)));
      int nin = n0 + dl - 1536;
      int h = nin >> 6, dd = nin & 63;
      *(uint4*)(vT + (((size_t)(b * H_ + h) * HS + dd) << 10) + t0base + tch * 8) = val;
    }
  }
}

// ---------------------------------------------------------------- attention
// Block = (head bh, 256-row q-chunk), 8 warps x 32 q-rows, 512 threads.
// Swapped QK^T (mfma(K,Q)) -> P^T lane-local; ReLU/scale/mask in-register;
// cvt_pk -> PV A-frag with NO cross-lane ops (A-slot order matched by V-row
// read order -> k-permutation-invariant). K/V: 3-stage LDS pipeline,
// counted vmcnt(2). Causal: warp drops out exactly past its diagonal.
__global__ __launch_bounds__(512, 4) void attn_relu(
    const ushort* __restrict__ q, const ushort* __restrict__ k,
    const ushort* __restrict__ vT, float* __restrict__ out) {
  __shared__ __align__(16) char smem[49152];  // 3 x (K 8KB | V 8KB)
  const int tid = threadIdx.x, lane = tid & 63, w = tid >> 6;
  const int l31 = lane & 31, h = lane >> 5;
  const int raw = blockIdx.x;
  const int chunk = 3 - (raw / 96);            // heavy chunks first
  const int bh = raw % 96;
  const size_t base = (size_t)bh * (T_ * HS);
  const int q0w = chunk * 256 + w * 32;        // warp's first q-row
  const int nkt = chunk * 4 + 4;               // k-tiles for this block

  // Q B-fragments (4 d-steps), straight from global
  bf16x8 qf[4];
  #pragma unroll
  for (int s = 0; s < 4; ++s)
    qf[s] = *(const bf16x8*)(q + base + (size_t)(q0w + l31) * HS + s * 16 + h * 8);

  // staging: 512 threads, 1 slot K + 1 slot V each; pre-swizzled source
  const int rowS = tid >> 3;
  const int colS = ((tid & 7) ^ (rowS & 7)) * 8;
  const int dstS = tid * 16;

#define STAGE_KV(bb_, kt) do { \
    GLOAD16(k  + base + (size_t)((kt) * 64 + rowS) * HS + colS, (bb_) + dstS); \
    GLOAD16(vT + base + (size_t)rowS * T_ + (kt) * 64 + colS, (bb_) + 8192 + dstS); \
  } while (0)

  f32x16 yacc0 = {}, yacc1 = {};

#define ATTN_TILE(cb_, kt) do { \
    const char* Kb = (cb_); \
    const char* Vb = (cb_) + 8192; \
    _Pragma("unroll") \
    for (int kr = 0; kr < 2; ++kr) { \
      int kbase = (kt) * 64 + kr * 32; \
      if (kbase <= q0w + 31) { \
        f32x16 sacc = {}; \
        int arow = kr * 32 + l31; \
        __builtin_amdgcn_s_setprio(1); \
        _Pragma("unroll") \
        for (int s = 0; s < 4; ++s) { \
          bf16x8 kf = *(const bf16x8*)(Kb + arow * 128 + (((2 * s + h) ^ (arow & 7)) << 4)); \
          sacc = __builtin_amdgcn_mfma_f32_32x32x16_bf16(kf, qf[s], sacc, 0, 0, 0); \
        } \
        __builtin_amdgcn_s_setprio(0); \
        const bool fullk = (kbase + 31 <= q0w); \
        uint wds[8]; \
        _Pragma("unroll") \
        for (int i = 0; i < 8; ++i) { \
          float a = fmaxf(sacc[2 * i] * 0.125f, 0.0f); \
          float b = fmaxf(sacc[2 * i + 1] * 0.125f, 0.0f); \
          if (!fullk) { \
            int r0 = 2 * i, r1 = 2 * i + 1; \
            if (kbase + (r0 & 3) + 8 * (r0 >> 2) + 4 * h > q0w + l31) a = 0.0f; \
            if (kbase + (r1 & 3) + 8 * (r1 >> 2) + 4 * h > q0w + l31) b = 0.0f; \
          } \
          wds[i] = cvtpk(a, b); \
        } \
        __builtin_amdgcn_s_setprio(1); \
        _Pragma("unroll") \
        for (int t = 0; t < 2; ++t) { \
          int4 pw = { (int)wds[4 * t], (int)wds[4 * t + 1], \
                      (int)wds[4 * t + 2], (int)wds[4 * t + 3] }; \
          bf16x8 pa = __builtin_bit_cast(bf16x8, pw); \
          _Pragma("unroll") \
          for (int dt = 0; dt < 2; ++dt) { \
            int d = dt * 32 + l31; \
            uint2 lo = *(const uint2*)(Vb + d * 128 + (((4 * kr + 2 * t) ^ (d & 7)) << 4) + 8 * h); \
            uint2 hi = *(const uint2*)(Vb + d * 128 + (((4 * kr + 2 * t + 1) ^ (d & 7)) << 4) + 8 * h); \
            int4 vv = { (int)lo.x, (int)lo.y, (int)hi.x, (int)hi.y }; \
            bf16x8 vf = __builtin_bit_cast(bf16x8, vv); \
            if (dt == 0) yacc0 = __builtin_amdgcn_mfma_f32_32x32x16_bf16(pa, vf, yacc0, 0, 0, 0); \
            else         yacc1 = __builtin_amdgcn_mfma_f32_32x32x16_bf16(pa, vf, yacc1, 0, 0, 0); \
          } \
        } \
        __builtin_amdgcn_s_setprio(0); \
      } \
    } \
  } while (0)

  STAGE_KV(smem, 0);
  if (nkt > 1) STAGE_KV(smem + 16384, 1);
  char* cptr = smem;
  char* sptr = smem + 32768;
  for (int kt = 0; kt < nkt - 1; ++kt) {
    WAITCNT_VM(2);                     // stage kt done; kt+1 stays in flight
    __builtin_amdgcn_s_barrier();
    if (kt + 2 < nkt) STAGE_KV(sptr, kt + 2);
    ATTN_TILE(cptr, kt);
    cptr += 16384; if (cptr == smem + 49152) cptr = smem;
    sptr += 16384; if (sptr == smem + 49152) sptr = smem;
  }
  WAITCNT_VM(0);
  __builtin_amdgcn_s_barrier();
  ATTN_TILE(cptr, nkt - 1);

  // epilogue: D map col=d (l31 + 32*dt), row q = q0w + (r&3)+8*(r>>2)+4h
  const int bb = bh / H_, hh = bh % H_;
  #pragma unroll
  for (int r = 0; r < 16; ++r) {
    int qrow = q0w + (r & 3) + 8 * (r >> 2) + 4 * h;
    float* op = out + (size_t)(bb * T_ + qrow) * C_ + hh * HS;
    op[l31] = yacc0[r];
    op[32 + l31] = yacc1[r];
  }
}

// ---------------------------------------------------------------- launch
extern "C" void kernel_launch(void* const* d_in, const int* in_sizes, int n_in,
                              void* d_out, int out_size, void* d_ws, size_t ws_size,
                              hipStream_t stream) {
  const float* x    = (const float*)d_in[0];
  const float* W    = (const float*)d_in[1];
  const float* bias = (const float*)d_in[2];
  float* out = (float*)d_out;

  char* ws = (char*)d_ws;
  ushort* xb = (ushort*)ws;                       // 8192*768*2  = 12582912 B
  ushort* wb = (ushort*)(ws + 12582912);          // 2304*768*2  =  3538944 B
  ushort* qb = (ushort*)(ws + 16121856);          // 12582912 B
  ushort* kb = (ushort*)(ws + 28704768);          // 12582912 B
  ushort* vT = (ushort*)(ws + 41287680);          // 12582912 B  [B,H,hs,T]

  cvt_bf16<<<2048, 256, 0, stream>>>(x, W, xb, wb);
  qkv_gemm<<<1152, 256, 0, stream>>>(xb, wb, bias, qb, kb, vT);
  attn_relu<<<384, 512, 0, stream>>>(qb, kb, vT, out);
}

// Round 6
// 148.471 us; speedup vs baseline: 1.1228x; 1.0339x over previous
//
#include <hip/hip_runtime.h>
#include <hip/hip_bf16.h>
#include <stdint.h>

// Problem constants: B=8, T=1024, C=768, H=12, hs=64
#define T_ 1024
#define C_ 768
#define H_ 12
#define HS 64

typedef __attribute__((ext_vector_type(8))) short bf16x8;
typedef __attribute__((ext_vector_type(4))) float f32x4;
typedef __attribute__((ext_vector_type(16))) float f32x16;

#define GLOAD16(g, l) __builtin_amdgcn_global_load_lds( \
    (const __attribute__((address_space(1))) uint32_t*)(g), \
    (__attribute__((address_space(3))) uint32_t*)(l), 16, 0, 0)

#define WAITCNT_VM(n) asm volatile("s_waitcnt vmcnt(" #n ")" ::: "memory")

__device__ __forceinline__ ushort f2b(float f) {
  uint32_t u = __builtin_bit_cast(uint32_t, f);
  u = (u + 0x7fffu + ((u >> 16) & 1u)) >> 16;   // RNE
  return (ushort)u;
}

__device__ __forceinline__ uint cvtpk(float a, float b) {
  uint r;
  asm("v_cvt_pk_bf16_f32 %0, %1, %2" : "=v"(r) : "v"(a), "v"(b));
  return r;   // low16 = bf16(a), high16 = bf16(b)
}

// ---------------------------------------------------------------- convert
__global__ __launch_bounds__(256) void cvt_bf16(
    const float* __restrict__ x, const float* __restrict__ wt,
    ushort* __restrict__ xb, ushort* __restrict__ wb) {
  const int NX4 = 8192 * 768 / 4;
  const int NW4 = 2304 * 768 / 4;
  int i = blockIdx.x * 256 + threadIdx.x;
  int stride = gridDim.x * 256;
  for (int idx = i; idx < NX4; idx += stride) {
    float4 f = ((const float4*)x)[idx];
    ushort4 o;
    o.x = f2b(f.x); o.y = f2b(f.y); o.z = f2b(f.z); o.w = f2b(f.w);
    ((ushort4*)xb)[idx] = o;
  }
  for (int idx = i; idx < NW4; idx += stride) {
    float4 f = ((const float4*)wt)[idx];
    ushort4 o;
    o.x = f2b(f.x); o.y = f2b(f.y); o.z = f2b(f.z); o.w = f2b(f.w);
    ((ushort4*)wb)[idx] = o;
  }
}

// ---------------------------------------------------------------- qkv gemm
// 128(m) x 256(n) tile, BK=32, 8 waves (512 thr), wave tile 64x64.
// 3-stage LDS pipeline (72KB -> 2 blocks/CU = 16 waves/CU), depth-2
// prefetch, counted vmcnt(3) + raw s_barrier (never 0 mid-loop).
// XCD-bijective swizzle (576 = 8*72). Q/K scatter [B,H,T,hs];
// V written transposed [B,H,hs,T] via in-LDS transpose.
__global__ __launch_bounds__(512, 4) void qkv_gemm(
    const ushort* __restrict__ xb, const ushort* __restrict__ wb,
    const float* __restrict__ bias,
    ushort* __restrict__ qo, ushort* __restrict__ ko, ushort* __restrict__ vT) {
  __shared__ __align__(16) char smem[73728];   // 3 x (A 8KB + B 16KB)
  const int tid = threadIdx.x, lane = tid & 63, w = tid >> 6;
  const int g = lane >> 4, l15 = lane & 15;
  const int id = blockIdx.x;
  const int wg = (id & 7) * 72 + (id >> 3);    // bijective: 576 = 8*72
  const int m0 = (wg / 9) * 128, n0 = (wg % 9) * 256;
  const int wr = w >> 2, wc = w & 3;           // 2(m) x 4(n) wave grid
  f32x4 acc[4][4] = {};

  // staging: A 128x32 = 512 16B-slots (1/thread), B 256x32 = 1024 (2/thread)
  const ushort* srcA;
  const ushort* srcB[2];
  int dstA, dstB[2];
  {
    int p = tid, row = p >> 2, s = p & 3;
    srcA = xb + (size_t)(m0 + row) * 768 + (s ^ ((row >> 1) & 3)) * 8;
    dstA = p * 16;
  }
  #pragma unroll
  for (int c = 0; c < 2; ++c) {
    int p = c * 512 + tid, row = p >> 2, s = p & 3;
    srcB[c] = wb + (size_t)(n0 + row) * 768 + (s ^ ((row >> 1) & 3)) * 8;
    dstB[c] = 8192 + p * 16;
  }

#define STAGE_G(bb_, k0) do { \
    GLOAD16(srcA + (k0), (bb_) + dstA); \
    GLOAD16(srcB[0] + (k0), (bb_) + dstB[0]); \
    GLOAD16(srcB[1] + (k0), (bb_) + dstB[1]); \
  } while (0)

#define GEMM_COMPUTE(cb_) do { \
    bf16x8 af[4], bfr[4]; \
    _Pragma("unroll") \
    for (int mi = 0; mi < 4; ++mi) { \
      int r_ = wr * 64 + mi * 16 + l15; \
      af[mi] = *(const bf16x8*)((cb_) + r_ * 64 + ((g ^ ((r_ >> 1) & 3)) << 4)); \
    } \
    _Pragma("unroll") \
    for (int ni = 0; ni < 4; ++ni) { \
      int r_ = wc * 64 + ni * 16 + l15; \
      bfr[ni] = *(const bf16x8*)((cb_) + 8192 + r_ * 64 + ((g ^ ((r_ >> 1) & 3)) << 4)); \
    } \
    __builtin_amdgcn_s_setprio(1); \
    _Pragma("unroll") \
    for (int mi = 0; mi < 4; ++mi) \
      _Pragma("unroll") \
      for (int ni = 0; ni < 4; ++ni) \
        acc[mi][ni] = __builtin_amdgcn_mfma_f32_16x16x32_bf16(af[mi], bfr[ni], acc[mi][ni], 0, 0, 0); \
    __builtin_amdgcn_s_setprio(0); \
  } while (0)

  STAGE_G(smem, 0);
  STAGE_G(smem + 24576, 32);
  char* cptr = smem;
  char* sptr = smem + 49152;
  for (int kk = 0; kk < 24; ++kk) {
    if (kk < 23) WAITCNT_VM(3);   // oldest stage landed; next stays in flight
    else         WAITCNT_VM(0);
    __builtin_amdgcn_s_barrier();
    if (kk < 22) STAGE_G(sptr, (kk + 2) * 32);
    GEMM_COMPUTE(cptr);
    cptr += 24576; if (cptr == smem + 73728) cptr = smem;
    sptr += 24576; if (sptr == smem + 73728) sptr = smem;
  }
  __syncthreads();   // all waves done with LDS before epilogue reuse

  const int which = n0 / 768;   // 768 % 256 == 0 -> block-uniform, no straddle
  if (which < 2) {
    ushort* outp = (which == 0) ? qo : ko;
    // acc -> LDS [ml][nl] (row stride 512B, XOR swizzle), 16B/lane stores
    #pragma unroll
    for (int ni = 0; ni < 4; ++ni) {
      int nl = wc * 64 + ni * 16 + l15;
      float bn = bias[n0 + nl];
      #pragma unroll
      for (int mi = 0; mi < 4; ++mi) {
        #pragma unroll
        for (int r = 0; r < 4; ++r) {
          int ml = wr * 64 + mi * 16 + g * 4 + r;
          *(ushort*)(smem + ml * 512 + ((nl * 2) ^ ((ml & 7) << 4))) =
              f2b(acc[mi][ni][r] + bn);
        }
      }
    }
    __syncthreads();
    #pragma unroll
    for (int c = 0; c < 8; ++c) {
      int p = c * 512 + tid;
      int ml = p >> 5, nch = p & 31;
      uint4 val = *(const uint4*)(smem + ml * 512 + ((nch * 16) ^ ((ml & 7) << 4)));
      int m = m0 + ml;
      int nin = n0 + nch * 8 - which * 768;
      int h = nin >> 6, d = nin & 63;
      *(uint4*)(outp + ((size_t)((m >> 10) * H_ + h) * T_ + (m & (T_ - 1))) * HS + d) = val;
    }
  } else {
    // V: transpose 128x256 through LDS ([dl 256][tl 128], stride 256B)
    #pragma unroll
    for (int ni = 0; ni < 4; ++ni) {
      int dl = wc * 64 + ni * 16 + l15;
      float bn = bias[n0 + dl];
      #pragma unroll
      for (int mi = 0; mi < 4; ++mi) {
        #pragma unroll
        for (int r = 0; r < 4; ++r) {
          int tl = wr * 64 + mi * 16 + g * 4 + r;
          *(ushort*)(smem + dl * 256 + ((tl * 2) ^ ((dl & 7) << 4))) =
              f2b(acc[mi][ni][r] + bn);
        }
      }
    }
    __syncthreads();
    const int b = m0 >> 10, t0base = m0 & 1023;
    #pragma unroll
    for (int c = 0; c < 8; ++c) {
      int p = c * 512 + tid;
      int dl = p >> 4, tch = p & 15;
      uint4 val = *(const uint4*)(smem + dl * 256 + ((tch * 16) ^ ((dl & 7) << 4)));
      int nin = n0 + dl - 1536;
      int h = nin >> 6, dd = nin & 63;
      *(uint4*)(vT + (((size_t)(b * H_ + h) * HS + dd) << 10) + t0base + tch * 8) = val;
    }
  }
}

// ---------------------------------------------------------------- attention
// Block = (head bh, 256-row q-chunk), 8 warps x 32 q-rows, 512 threads.
// Swapped QK^T (mfma(K,Q)) -> P^T lane-local; ReLU/scale/mask in-register;
// cvt_pk -> PV A-frag with NO cross-lane ops (A-slot order matched by V-row
// read order -> k-permutation-invariant). K/V: 3-stage LDS pipeline,
// counted vmcnt(2). Causal: warp drops out exactly past its diagonal.
__global__ __launch_bounds__(512, 4) void attn_relu(
    const ushort* __restrict__ q, const ushort* __restrict__ k,
    const ushort* __restrict__ vT, float* __restrict__ out) {
  __shared__ __align__(16) char smem[49152];  // 3 x (K 8KB | V 8KB)
  const int tid = threadIdx.x, lane = tid & 63, w = tid >> 6;
  const int l31 = lane & 31, h = lane >> 5;
  const int raw = blockIdx.x;
  const int chunk = 3 - (raw / 96);            // heavy chunks first
  const int bh = raw % 96;
  const size_t base = (size_t)bh * (T_ * HS);
  const int q0w = chunk * 256 + w * 32;        // warp's first q-row
  const int nkt = chunk * 4 + 4;               // k-tiles for this block

  // Q B-fragments (4 d-steps), straight from global
  bf16x8 qf[4];
  #pragma unroll
  for (int s = 0; s < 4; ++s)
    qf[s] = *(const bf16x8*)(q + base + (size_t)(q0w + l31) * HS + s * 16 + h * 8);

  // staging: 512 threads, 1 slot K + 1 slot V each; pre-swizzled source
  const int rowS = tid >> 3;
  const int colS = ((tid & 7) ^ (rowS & 7)) * 8;
  const int dstS = tid * 16;

#define STAGE_KV(bb_, kt) do { \
    GLOAD16(k  + base + (size_t)((kt) * 64 + rowS) * HS + colS, (bb_) + dstS); \
    GLOAD16(vT + base + (size_t)rowS * T_ + (kt) * 64 + colS, (bb_) + 8192 + dstS); \
  } while (0)

  f32x16 yacc0 = {}, yacc1 = {};

#define ATTN_TILE(cb_, kt) do { \
    const char* Kb = (cb_); \
    const char* Vb = (cb_) + 8192; \
    _Pragma("unroll") \
    for (int kr = 0; kr < 2; ++kr) { \
      int kbase = (kt) * 64 + kr * 32; \
      if (kbase <= q0w + 31) { \
        f32x16 sacc = {}; \
        int arow = kr * 32 + l31; \
        __builtin_amdgcn_s_setprio(1); \
        _Pragma("unroll") \
        for (int s = 0; s < 4; ++s) { \
          bf16x8 kf = *(const bf16x8*)(Kb + arow * 128 + (((2 * s + h) ^ (arow & 7)) << 4)); \
          sacc = __builtin_amdgcn_mfma_f32_32x32x16_bf16(kf, qf[s], sacc, 0, 0, 0); \
        } \
        __builtin_amdgcn_s_setprio(0); \
        const bool fullk = (kbase + 31 <= q0w); \
        uint wds[8]; \
        _Pragma("unroll") \
        for (int i = 0; i < 8; ++i) { \
          float a = fmaxf(sacc[2 * i] * 0.125f, 0.0f); \
          float b = fmaxf(sacc[2 * i + 1] * 0.125f, 0.0f); \
          if (!fullk) { \
            int r0 = 2 * i, r1 = 2 * i + 1; \
            if (kbase + (r0 & 3) + 8 * (r0 >> 2) + 4 * h > q0w + l31) a = 0.0f; \
            if (kbase + (r1 & 3) + 8 * (r1 >> 2) + 4 * h > q0w + l31) b = 0.0f; \
          } \
          wds[i] = cvtpk(a, b); \
        } \
        __builtin_amdgcn_s_setprio(1); \
        _Pragma("unroll") \
        for (int t = 0; t < 2; ++t) { \
          int4 pw = { (int)wds[4 * t], (int)wds[4 * t + 1], \
                      (int)wds[4 * t + 2], (int)wds[4 * t + 3] }; \
          bf16x8 pa = __builtin_bit_cast(bf16x8, pw); \
          _Pragma("unroll") \
          for (int dt = 0; dt < 2; ++dt) { \
            int d = dt * 32 + l31; \
            uint2 lo = *(const uint2*)(Vb + d * 128 + (((4 * kr + 2 * t) ^ (d & 7)) << 4) + 8 * h); \
            uint2 hi = *(const uint2*)(Vb + d * 128 + (((4 * kr + 2 * t + 1) ^ (d & 7)) << 4) + 8 * h); \
            int4 vv = { (int)lo.x, (int)lo.y, (int)hi.x, (int)hi.y }; \
            bf16x8 vf = __builtin_bit_cast(bf16x8, vv); \
            if (dt == 0) yacc0 = __builtin_amdgcn_mfma_f32_32x32x16_bf16(pa, vf, yacc0, 0, 0, 0); \
            else         yacc1 = __builtin_amdgcn_mfma_f32_32x32x16_bf16(pa, vf, yacc1, 0, 0, 0); \
          } \
        } \
        __builtin_amdgcn_s_setprio(0); \
      } \
    } \
  } while (0)

  STAGE_KV(smem, 0);
  if (nkt > 1) STAGE_KV(smem + 16384, 1);
  char* cptr = smem;
  char* sptr = smem + 32768;
  for (int kt = 0; kt < nkt - 1; ++kt) {
    WAITCNT_VM(2);                     // stage kt done; kt+1 stays in flight
    __builtin_amdgcn_s_barrier();
    if (kt + 2 < nkt) STAGE_KV(sptr, kt + 2);
    ATTN_TILE(cptr, kt);
    cptr += 16384; if (cptr == smem + 49152) cptr = smem;
    sptr += 16384; if (sptr == smem + 49152) sptr = smem;
  }
  WAITCNT_VM(0);
  __builtin_amdgcn_s_barrier();
  ATTN_TILE(cptr, nkt - 1);

  // epilogue: D map col=d (l31 + 32*dt), row q = q0w + (r&3)+8*(r>>2)+4h
  const int bb = bh / H_, hh = bh % H_;
  #pragma unroll
  for (int r = 0; r < 16; ++r) {
    int qrow = q0w + (r & 3) + 8 * (r >> 2) + 4 * h;
    float* op = out + (size_t)(bb * T_ + qrow) * C_ + hh * HS;
    op[l31] = yacc0[r];
    op[32 + l31] = yacc1[r];
  }
}

// ---------------------------------------------------------------- launch
extern "C" void kernel_launch(void* const* d_in, const int* in_sizes, int n_in,
                              void* d_out, int out_size, void* d_ws, size_t ws_size,
                              hipStream_t stream) {
  const float* x    = (const float*)d_in[0];
  const float* W    = (const float*)d_in[1];
  const float* bias = (const float*)d_in[2];
  float* out = (float*)d_out;

  char* ws = (char*)d_ws;
  ushort* xb = (ushort*)ws;                       // 8192*768*2  = 12582912 B
  ushort* wb = (ushort*)(ws + 12582912);          // 2304*768*2  =  3538944 B
  ushort* qb = (ushort*)(ws + 16121856);          // 12582912 B
  ushort* kb = (ushort*)(ws + 28704768);          // 12582912 B
  ushort* vT = (ushort*)(ws + 41287680);          // 12582912 B  [B,H,hs,T]

  cvt_bf16<<<2048, 256, 0, stream>>>(x, W, xb, wb);
  qkv_gemm<<<576, 512, 0, stream>>>(xb, wb, bias, qb, kb, vT);
  attn_relu<<<384, 512, 0, stream>>>(qb, kb, vT, out);
}